// Round 13
// baseline (19.229 us; speedup 1.0000x reference)
//
#include <hip/hip_runtime.h>
#include <hip/hip_bf16.h>

// S=128, Q=8192, H=230
//   logits[s,q] = a[s] + c[q] + b - 2*sum_k wx[s,k]*y[q,k]
//   a[s]=sum w*x^2 (f32), c[q]=sum w*y^2 (f32), dot via bf16 MFMA (f32 acc).
// r12 (18.9us) + three latency cuts:
//   (1) A-frags prefetched into registers BEFORE the staging barrier
//       (compiler can't hoist global loads past __syncthreads itself)
//   (2) phase order: cpart -> MFMA (all operands resident) per region
//   (3) wave-parallel cq reduce (wave 0, shfl_xor butterfly, fixed order)
// All reductions fixed-order (graph replay must be bitwise identical).

#define S_DIM 128
#define Q_DIM 8192
#define H_DIM 230
#define K2    256              // bf16 K padded to multiple of 32
#define SQ    (S_DIM * Q_DIM)
#define QB    16               // q-tile per block
#define NBLK  (Q_DIM / QB)     // 512 main blocks

using short8 = __attribute__((ext_vector_type(8))) short;   // 8 bf16 (4 VGPRs)
using f32x4  = __attribute__((ext_vector_type(4))) float;

__device__ __forceinline__ float bf16_to_f32(short bits) {
    unsigned u = ((unsigned)(unsigned short)bits) << 16;
    return __uint_as_float(u);
}
__device__ __forceinline__ unsigned short bf16bits(float f) {
    __hip_bfloat16 h = __float2bfloat16(f);
    return *reinterpret_cast<unsigned short*>(&h);
}
__device__ __forceinline__ unsigned packbf2(float lo, float hi) {
    return (unsigned)bf16bits(lo) | ((unsigned)bf16bits(hi) << 16);
}

// ---------------- Kernel 1: prep ----------------
// grid=128, block=256(==K2). xwb[s][k]=bf16(w*x), zero-padded; asum[s]=sum w*x^2.
__global__ __launch_bounds__(256) void prep_kernel(
    const float* __restrict__ x, const float* __restrict__ w,
    __hip_bfloat16* __restrict__ xwb, float* __restrict__ asum)
{
    __shared__ float lred[4];
    const int tid = threadIdx.x, s = blockIdx.x;
    float xv = 0.f, wv = 0.f;
    if (tid < H_DIM) { xv = x[s * H_DIM + tid]; wv = w[tid]; }
    float wx = wv * xv;
    xwb[s * K2 + tid] = __float2bfloat16(wx);   // 0 for tid>=230

    float p = wx * xv;                          // w*x^2
    #pragma unroll
    for (int off = 32; off >= 1; off >>= 1) p += __shfl_down(p, off, 64);
    if ((tid & 63) == 0) lred[tid >> 6] = p;
    __syncthreads();
    if (tid == 0) asum[s] = lred[0] + lred[1] + lred[2] + lred[3];
}

// ---------------- Kernel 2: main (MFMA GEMM + sigmoid + BCE) ----------------
// grid=512, block=512 (8 waves). Block: all 128 s x 16 q.
// Wave wid: s in [16*wid, 16*wid+16), one 16x16 MFMA tile (single acc).
__global__ __launch_bounds__(512, 4) void main_kernel(
    const float* __restrict__ y, const int* __restrict__ label,
    const __hip_bfloat16* __restrict__ xwb, const float* __restrict__ asum,
    const float* __restrict__ w, const float* __restrict__ bptr,
    float* __restrict__ out, float* __restrict__ lossws)
{
    __shared__ __align__(16) short ylb[QB * K2];   // 8 KB bf16, XOR-swizzled
    __shared__ float cpart[32][17];
    __shared__ float cq[QB];
    __shared__ float asl[S_DIM];
    __shared__ float lred[8];

    const int tid = threadIdx.x;
    const int q0 = blockIdx.x * QB;
    const int wid = tid >> 6, l = tid & 63;
    const int lm = l & 15, lh = l >> 4;
    const int s_base = wid * 16;
    const int qg = q0 + lm;
    char* ylc = reinterpret_cast<char*>(ylb);

    if (tid < S_DIM) asl[tid] = asum[tid];

    // ---- stage y tile (16 rows x 230 f32) -> bf16 swizzled LDS ----
    // Each aligned float4 (e = 4*i4, e even, rows start at even offsets since
    // H=230 even) splits into two row-contained even-column bf16 pairs ->
    // two packed ds_write_b32 (4-byte aligned; swizzle XOR touches bits>=4).
    const float4* ysrc4 = reinterpret_cast<const float4*>(y + (size_t)q0 * H_DIM);
    #pragma unroll
    for (int it = 0; it < 2; ++it) {
        int i4 = tid + 512 * it;
        if (i4 < (QB * H_DIM) / 4) {
            float4 v = ysrc4[i4];
            int e0 = i4 * 4;
            int r0 = e0 / H_DIM;               // const divide -> magic mul
            int c0 = e0 - r0 * H_DIM;          // even
            int e2 = e0 + 2;
            int r2 = e2 / H_DIM;
            int c2 = e2 - r2 * H_DIM;          // even
            int byt0 = ((r0 << 9) + (c0 << 1)) ^ ((r0 & 7) << 4);
            int byt2 = ((r2 << 9) + (c2 << 1)) ^ ((r2 & 7) << 4);
            *reinterpret_cast<unsigned*>(ylc + byt0) = packbf2(v.x, v.y);
            *reinterpret_cast<unsigned*>(ylc + byt2) = packbf2(v.z, v.w);
        }
    }
    if (tid < QB * (K2 - H_DIM) / 2) {   // zero-fill k=230..255: 16 rows x 13 pairs
        int r = tid & 15, c = H_DIM + 2 * (tid >> 4);
        int byt = ((r << 9) + (c << 1)) ^ ((r & 7) << 4);
        *reinterpret_cast<unsigned*>(ylc + byt) = 0u;
    }

    // ---- prefetches issued AFTER staging reads, consumed post-barrier ----
    // (compiler will not hoist global loads above __syncthreads, so manual
    //  prefetch is required; loads stay in flight under the staging stores)
    int labs[4];
    #pragma unroll
    for (int r = 0; r < 4; ++r)
        labs[r] = label[(size_t)(s_base + lh * 4 + r) * Q_DIM + qg];

    short8 afr[8];                             // A row = s_base+lm, k=ks*32+lh*8
    const short* A = reinterpret_cast<const short*>(xwb) + (s_base + lm) * K2 + lh * 8;
    #pragma unroll
    for (int ks = 0; ks < 8; ++ks)
        afr[ks] = *reinterpret_cast<const short8*>(A + ks * 32);

    __syncthreads();

    // ---- c[q] partials (VALU; covers A-load tail) ----
    {
        const int r = tid & 15, ch = tid >> 4;     // ch in 0..31
        const int k0 = ch * 8;
        int byt = ((r << 9) + (k0 << 1)) ^ ((r & 7) << 4);
        short8 v8 = *reinterpret_cast<const short8*>(ylc + byt);
        float p = 0.f;
        #pragma unroll
        for (int j = 0; j < 8; ++j) {
            float v = bf16_to_f32(v8[j]);
            float wk = (k0 + j < H_DIM) ? w[k0 + j] : 0.f;
            p = fmaf(wk * v, v, p);
        }
        cpart[ch][r] = p;
    }

    // ---- MFMA k-loop: all operands resident (afr regs + LDS tile) ----
    f32x4 acc = {0.f, 0.f, 0.f, 0.f};
    #pragma unroll
    for (int ks = 0; ks < K2 / 32; ++ks) {
        const int kof = ks * 32 + lh * 8;
        int byt = ((lm << 9) + (kof << 1)) ^ ((lm & 7) << 4);
        short8 bf = *reinterpret_cast<const short8*>(ylc + byt);
        acc = __builtin_amdgcn_mfma_f32_16x16x32_bf16(afr[ks], bf, acc, 0, 0, 0);
    }
    __syncthreads();

    // ---- cq reduce: wave 0, 4 lanes per q, fixed order ----
    if (wid == 0) {
        const int q = l & 15, g = l >> 4;          // g in 0..3, 8 chunks each
        float p = 0.f;
        #pragma unroll
        for (int j = 0; j < 8; ++j) p += cpart[g * 8 + j][q];
        p += __shfl_xor(p, 16, 64);
        p += __shfl_xor(p, 32, 64);
        if (g == 0) cq[q] = p + bptr[0];           // fold bias in
    }
    __syncthreads();

    // ---- epilogue: z = a[s]+c[q]+b-2*dot ; sigmoid -> out ; BCE partial ----
    // bce = z*(1-lab) + log(1+exp(-z)), sharing exp(-z) with the sigmoid.
    float lsum = 0.f;
    const float cqv = cq[lm];
    #pragma unroll
    for (int r = 0; r < 4; ++r) {
        int s = s_base + lh * 4 + r;               // D row=(l>>4)*4+r, col=l&15
        float z = asl[s] + cqv - 2.0f * acc[r];
        float ez = __expf(-z);
        float sc = 1.0f / (1.0f + ez);
        size_t o = (size_t)s * Q_DIM + qg;
        out[o] = sc;
        float lab = (float)labs[r];
        float bce = z * (1.0f - lab) + __logf(1.0f + ez);
        lsum += bce;
    }
    #pragma unroll
    for (int off = 32; off >= 1; off >>= 1) lsum += __shfl_down(lsum, off, 64);
    if (l == 0) lred[wid] = lsum;
    __syncthreads();
    if (tid == 0) {
        float blk = 0.f;
        #pragma unroll
        for (int i = 0; i < 8; ++i) blk += lred[i];
        lossws[blockIdx.x] = blk;
    }
}

// ---------------- Kernel 3: deterministic loss reduce ----------------
__global__ __launch_bounds__(256) void loss_reduce_kernel(
    const float* __restrict__ lossws, float* __restrict__ out)
{
    __shared__ float lred[4];
    const int tid = threadIdx.x;
    float p = lossws[tid] + lossws[tid + 256];     // NBLK=512 partials
    #pragma unroll
    for (int off = 32; off >= 1; off >>= 1) p += __shfl_down(p, off, 64);
    if ((tid & 63) == 0) lred[tid >> 6] = p;
    __syncthreads();
    if (tid == 0)
        out[SQ] = (lred[0] + lred[1] + lred[2] + lred[3]) * (1.0f / (float)SQ);
}

extern "C" void kernel_launch(void* const* d_in, const int* in_sizes, int n_in,
                              void* d_out, int out_size, void* d_ws, size_t ws_size,
                              hipStream_t stream) {
    const float* x = (const float*)d_in[0];     // [128,230]
    const float* y = (const float*)d_in[1];     // [8192,230]
    const int* label = (const int*)d_in[2];     // [128,8192]
    const float* w = (const float*)d_in[3];     // [230]
    const float* b = (const float*)d_in[4];     // [1]
    float* out = (float*)d_out;                 // [128*8192 + 1]

    __hip_bfloat16* xwb = (__hip_bfloat16*)d_ws;            // [128][256] bf16 = 64 KB
    float* asum = (float*)((char*)d_ws + S_DIM * K2 * 2);   // [128]
    float* lossws = asum + S_DIM;                           // [512]

    prep_kernel<<<S_DIM, 256, 0, stream>>>(x, w, xwb, asum);
    main_kernel<<<NBLK, 512, 0, stream>>>(y, label, xwb, asum, w, b, out, lossws);
    loss_reduce_kernel<<<1, 256, 0, stream>>>(lossws, out);
}

// Round 14
// 17.665 us; speedup vs baseline: 1.0885x; 1.0885x over previous
//
#include <hip/hip_runtime.h>
#include <hip/hip_bf16.h>

// S=128, Q=8192, H=230
//   logits[s,q] = a[s] + c[q] + b - 2*sum_k wx[s,k]*y[q,k]
//   a[s]=sum w*x^2 (f32), c[q]=sum w*y^2 (f32), dot via bf16 MFMA (f32 acc).
// r12 structure (18.9us) with ONE delta: QB=32 (grid 256, 8 waves, each wave
// 16s x 32q via 2 accs sharing one A-frag set) -> halves per-block fixed
// costs and xwb L2 traffic.
// All reductions fixed-order (graph replay must be bitwise identical).

#define S_DIM 128
#define Q_DIM 8192
#define H_DIM 230
#define K2    256              // bf16 K padded to multiple of 32
#define SQ    (S_DIM * Q_DIM)
#define QB    32               // q-tile per block
#define NBLK  (Q_DIM / QB)     // 256 main blocks

using short8 = __attribute__((ext_vector_type(8))) short;   // 8 bf16 (4 VGPRs)
using f32x4  = __attribute__((ext_vector_type(4))) float;

__device__ __forceinline__ float bf16_to_f32(short bits) {
    unsigned u = ((unsigned)(unsigned short)bits) << 16;
    return __uint_as_float(u);
}
__device__ __forceinline__ unsigned short bf16bits(float f) {
    __hip_bfloat16 h = __float2bfloat16(f);
    return *reinterpret_cast<unsigned short*>(&h);
}
__device__ __forceinline__ unsigned packbf2(float lo, float hi) {
    return (unsigned)bf16bits(lo) | ((unsigned)bf16bits(hi) << 16);
}

// ---------------- Kernel 1: prep ----------------
// grid=128, block=256(==K2). xwb[s][k]=bf16(w*x), zero-padded; asum[s]=sum w*x^2.
__global__ __launch_bounds__(256) void prep_kernel(
    const float* __restrict__ x, const float* __restrict__ w,
    __hip_bfloat16* __restrict__ xwb, float* __restrict__ asum)
{
    __shared__ float lred[4];
    const int tid = threadIdx.x, s = blockIdx.x;
    float xv = 0.f, wv = 0.f;
    if (tid < H_DIM) { xv = x[s * H_DIM + tid]; wv = w[tid]; }
    float wx = wv * xv;
    xwb[s * K2 + tid] = __float2bfloat16(wx);   // 0 for tid>=230

    float p = wx * xv;                          // w*x^2
    #pragma unroll
    for (int off = 32; off >= 1; off >>= 1) p += __shfl_down(p, off, 64);
    if ((tid & 63) == 0) lred[tid >> 6] = p;
    __syncthreads();
    if (tid == 0) asum[s] = lred[0] + lred[1] + lred[2] + lred[3];
}

// ---------------- Kernel 2: main (MFMA GEMM + sigmoid + BCE) ----------------
// grid=256, block=512 (8 waves). Block: all 128 s x 32 q.
// Wave wid: s in [16*wid, 16*wid+16), q-halves [q0,q0+16) and [q0+16,q0+32).
__global__ __launch_bounds__(512, 4) void main_kernel(
    const float* __restrict__ y, const int* __restrict__ label,
    const __hip_bfloat16* __restrict__ xwb, const float* __restrict__ asum,
    const float* __restrict__ w, const float* __restrict__ bptr,
    float* __restrict__ out, float* __restrict__ lossws)
{
    __shared__ __align__(16) short ylb[QB * K2];   // 16 KB bf16, XOR-swizzled
    __shared__ float cpart[16][33];
    __shared__ float cq[QB];
    __shared__ float asl[S_DIM];
    __shared__ float lred[8];

    const int tid = threadIdx.x;
    const int q0 = blockIdx.x * QB;
    const int wid = tid >> 6, l = tid & 63;
    const int lm = l & 15, lh = l >> 4;
    const int s_base = wid * 16;
    char* ylc = reinterpret_cast<char*>(ylb);

    if (tid < S_DIM) asl[tid] = asum[tid];

    // ---- stage y tile (32 rows x 230 f32) -> bf16 swizzled LDS ----
    // One contiguous span of 32*230 = 7360 f32 = 1840 float4, 16B-aligned.
    // Each float4 splits into two row-contained even-column bf16 pairs ->
    // two packed ds_write_b32 (swizzle XOR touches bits>=4 only).
    const float4* ysrc4 = reinterpret_cast<const float4*>(y + (size_t)q0 * H_DIM);
    #pragma unroll
    for (int it = 0; it < 4; ++it) {
        int i4 = tid + 512 * it;
        if (i4 < (QB * H_DIM) / 4) {
            float4 v = ysrc4[i4];
            int e0 = i4 * 4;
            int r0 = e0 / H_DIM;               // const divide -> magic mul
            int c0 = e0 - r0 * H_DIM;          // even
            int e2 = e0 + 2;
            int r2 = e2 / H_DIM;
            int c2 = e2 - r2 * H_DIM;          // even
            int byt0 = ((r0 << 9) + (c0 << 1)) ^ ((r0 & 7) << 4);
            int byt2 = ((r2 << 9) + (c2 << 1)) ^ ((r2 & 7) << 4);
            *reinterpret_cast<unsigned*>(ylc + byt0) = packbf2(v.x, v.y);
            *reinterpret_cast<unsigned*>(ylc + byt2) = packbf2(v.z, v.w);
        }
    }
    if (tid < QB * (K2 - H_DIM) / 2) {   // zero-fill k=230..255: 32 rows x 13 pairs
        int r = tid & 31, c = H_DIM + 2 * (tid >> 5);
        int byt = ((r << 9) + (c << 1)) ^ ((r & 7) << 4);
        *reinterpret_cast<unsigned*>(ylc + byt) = 0u;
    }

    // ---- label prefetch: issue AFTER staging reads, consume in epilogue ----
    int labs[2][4];
    {
        const size_t ob = (size_t)(s_base + lh * 4) * Q_DIM + q0 + lm;
        #pragma unroll
        for (int r = 0; r < 4; ++r) {
            labs[0][r] = label[ob + (size_t)r * Q_DIM];
            labs[1][r] = label[ob + (size_t)r * Q_DIM + 16];
        }
    }

    __syncthreads();

    // ---- c[q] partials: r=tid&31 (q-row), ch=tid>>5 (16 k each) ----
    {
        const int r = tid & 31, ch = tid >> 5;     // ch in 0..15
        const int k0 = ch * 16;
        int byt0 = ((r << 9) + (k0 << 1)) ^ ((r & 7) << 4);
        int byt1 = ((r << 9) + ((k0 + 8) << 1)) ^ ((r & 7) << 4);
        short8 v8a = *reinterpret_cast<const short8*>(ylc + byt0);
        short8 v8b = *reinterpret_cast<const short8*>(ylc + byt1);
        float p = 0.f;
        #pragma unroll
        for (int j = 0; j < 8; ++j) {
            float va = bf16_to_f32(v8a[j]);
            float wa = (k0 + j < H_DIM) ? w[k0 + j] : 0.f;
            p = fmaf(wa * va, va, p);
        }
        #pragma unroll
        for (int j = 0; j < 8; ++j) {
            float vb = bf16_to_f32(v8b[j]);
            float wb = (k0 + 8 + j < H_DIM) ? w[k0 + 8 + j] : 0.f;
            p = fmaf(wb * vb, vb, p);
        }
        cpart[ch][r] = p;
    }
    __syncthreads();
    if (tid < QB) {
        float c = 0.f;
        #pragma unroll
        for (int ch = 0; ch < 16; ++ch) c += cpart[ch][tid];
        cq[tid] = c + bptr[0];                     // fold bias in
    }
    __syncthreads();

    // ---- MFMA k-loop: wave computes 16 s x 32 q (2 accs, shared A) ----
    f32x4 acc0 = {0.f, 0.f, 0.f, 0.f};
    f32x4 acc1 = {0.f, 0.f, 0.f, 0.f};
    const short* A = reinterpret_cast<const short*>(xwb) + (s_base + lm) * K2 + lh * 8;
    #pragma unroll
    for (int ks = 0; ks < K2 / 32; ++ks) {
        const int kof = ks * 32 + lh * 8;
        short8 a = *reinterpret_cast<const short8*>(A + ks * 32);
        int byt0 = ((lm << 9) + (kof << 1)) ^ ((lm & 7) << 4);
        int byt1 = (((lm + 16) << 9) + (kof << 1)) ^ ((lm & 7) << 4);
        short8 bf0 = *reinterpret_cast<const short8*>(ylc + byt0);
        short8 bf1 = *reinterpret_cast<const short8*>(ylc + byt1);
        acc0 = __builtin_amdgcn_mfma_f32_16x16x32_bf16(a, bf0, acc0, 0, 0, 0);
        acc1 = __builtin_amdgcn_mfma_f32_16x16x32_bf16(a, bf1, acc1, 0, 0, 0);
    }

    // ---- epilogue: z = a[s]+c[q]+b-2*dot ; sigmoid -> out ; BCE partial ----
    // bce = z*(1-lab) + log(1+exp(-z)), sharing exp(-z) with the sigmoid.
    float lsum = 0.f;
    const float cq0 = cq[lm], cq1 = cq[lm + 16];
    #pragma unroll
    for (int r = 0; r < 4; ++r) {
        int s = s_base + lh * 4 + r;               // D row=(l>>4)*4+r, col=l&15
        size_t o = (size_t)s * Q_DIM + q0 + lm;
        {
            float z = asl[s] + cq0 - 2.0f * acc0[r];
            float ez = __expf(-z);
            out[o] = 1.0f / (1.0f + ez);
            float lab = (float)labs[0][r];
            lsum += z * (1.0f - lab) + __logf(1.0f + ez);
        }
        {
            float z = asl[s] + cq1 - 2.0f * acc1[r];
            float ez = __expf(-z);
            out[o + 16] = 1.0f / (1.0f + ez);
            float lab = (float)labs[1][r];
            lsum += z * (1.0f - lab) + __logf(1.0f + ez);
        }
    }
    #pragma unroll
    for (int off = 32; off >= 1; off >>= 1) lsum += __shfl_down(lsum, off, 64);
    if (l == 0) lred[wid] = lsum;
    __syncthreads();
    if (tid == 0) {
        float blk = 0.f;
        #pragma unroll
        for (int i = 0; i < 8; ++i) blk += lred[i];
        lossws[blockIdx.x] = blk;
    }
}

// ---------------- Kernel 3: deterministic loss reduce ----------------
__global__ __launch_bounds__(256) void loss_reduce_kernel(
    const float* __restrict__ lossws, float* __restrict__ out)
{
    __shared__ float lred[4];
    const int tid = threadIdx.x;
    float p = lossws[tid];                         // NBLK=256 partials
    #pragma unroll
    for (int off = 32; off >= 1; off >>= 1) p += __shfl_down(p, off, 64);
    if ((tid & 63) == 0) lred[tid >> 6] = p;
    __syncthreads();
    if (tid == 0)
        out[SQ] = (lred[0] + lred[1] + lred[2] + lred[3]) * (1.0f / (float)SQ);
}

extern "C" void kernel_launch(void* const* d_in, const int* in_sizes, int n_in,
                              void* d_out, int out_size, void* d_ws, size_t ws_size,
                              hipStream_t stream) {
    const float* x = (const float*)d_in[0];     // [128,230]
    const float* y = (const float*)d_in[1];     // [8192,230]
    const int* label = (const int*)d_in[2];     // [128,8192]
    const float* w = (const float*)d_in[3];     // [230]
    const float* b = (const float*)d_in[4];     // [1]
    float* out = (float*)d_out;                 // [128*8192 + 1]

    __hip_bfloat16* xwb = (__hip_bfloat16*)d_ws;            // [128][256] bf16 = 64 KB
    float* asum = (float*)((char*)d_ws + S_DIM * K2 * 2);   // [128]
    float* lossws = asum + S_DIM;                           // [256]

    prep_kernel<<<S_DIM, 256, 0, stream>>>(x, w, xwb, asum);
    main_kernel<<<NBLK, 512, 0, stream>>>(y, label, xwb, asum, w, b, out, lossws);
    loss_reduce_kernel<<<1, 256, 0, stream>>>(lossws, out);
}

// Round 15
// 14.675 us; speedup vs baseline: 1.3103x; 1.2038x over previous
//
#include <hip/hip_runtime.h>
#include <hip/hip_bf16.h>

// S=128, Q=8192, H=230
//   logits[s,q] = a[s] + c[q] + b - 2*sum_k (w*x)[s,k]*y[q,k]
// r14 champion (17.7us, QB=32) with ONE structural delta: prep kernel deleted.
// Each wave builds its 16 A-rows bf16(w*x) in registers PRE-BARRIER from x/w
// (loads overlap y staging), a[s] via shfl_xor byproduct -> asl LDS.
// grid=256 (1 block/CU) so launch_bounds relaxed to (512,2) - no VGPR cliff.
// Loss: per-block partial + tiny deterministic reduce kernel (r10 lesson:
// fence-based last-block reduction costs +13us).

#define S_DIM 128
#define Q_DIM 8192
#define H_DIM 230
#define K2    256              // bf16 K padded to multiple of 32
#define SQ    (S_DIM * Q_DIM)
#define QB    32               // q-tile per block
#define NBLK  (Q_DIM / QB)     // 256 main blocks

using short8 = __attribute__((ext_vector_type(8))) short;   // 8 bf16 (4 VGPRs)
using f32x4  = __attribute__((ext_vector_type(4))) float;

__device__ __forceinline__ float bf16_to_f32(short bits) {
    unsigned u = ((unsigned)(unsigned short)bits) << 16;
    return __uint_as_float(u);
}
__device__ __forceinline__ unsigned short bf16bits(float f) {
    __hip_bfloat16 h = __float2bfloat16(f);
    return *reinterpret_cast<unsigned short*>(&h);
}
__device__ __forceinline__ unsigned packbf2(float lo, float hi) {
    return (unsigned)bf16bits(lo) | ((unsigned)bf16bits(hi) << 16);
}

// ---------------- Kernel 1: main (MFMA GEMM + sigmoid + BCE) ----------------
// grid=256, block=512 (8 waves). Block: all 128 s x 32 q.
// Wave wid: s in [16*wid, 16*wid+16), q-halves [q0,q0+16) and [q0+16,q0+32).
__global__ __launch_bounds__(512, 2) void main_kernel(
    const float* __restrict__ x, const float* __restrict__ y,
    const int* __restrict__ label, const float* __restrict__ w,
    const float* __restrict__ bptr, float* __restrict__ out,
    float* __restrict__ lossws)
{
    __shared__ __align__(16) short ylb[QB * K2];   // 16 KB bf16, XOR-swizzled
    __shared__ float cpart[16][33];
    __shared__ float cq[QB];
    __shared__ float asl[S_DIM];
    __shared__ float lred[8];

    const int tid = threadIdx.x;
    const int q0 = blockIdx.x * QB;
    const int wid = tid >> 6, l = tid & 63;
    const int lm = l & 15, lh = l >> 4;
    const int s_base = wid * 16;
    char* ylc = reinterpret_cast<char*>(ylb);

    // ---- stage y tile (32 rows x 230 f32) -> bf16 swizzled LDS ----
    // One contiguous span of 32*230 = 7360 f32 = 1840 float4, 16B-aligned.
    // Each float4 splits into two row-contained even-column bf16 pairs ->
    // two packed ds_write_b32 (swizzle XOR touches bits>=4 only).
    const float4* ysrc4 = reinterpret_cast<const float4*>(y + (size_t)q0 * H_DIM);
    #pragma unroll
    for (int it = 0; it < 4; ++it) {
        int i4 = tid + 512 * it;
        if (i4 < (QB * H_DIM) / 4) {
            float4 v = ysrc4[i4];
            int e0 = i4 * 4;
            int r0 = e0 / H_DIM;               // const divide -> magic mul
            int c0 = e0 - r0 * H_DIM;          // even
            int e2 = e0 + 2;
            int r2 = e2 / H_DIM;
            int c2 = e2 - r2 * H_DIM;          // even
            int byt0 = ((r0 << 9) + (c0 << 1)) ^ ((r0 & 7) << 4);
            int byt2 = ((r2 << 9) + (c2 << 1)) ^ ((r2 & 7) << 4);
            *reinterpret_cast<unsigned*>(ylc + byt0) = packbf2(v.x, v.y);
            *reinterpret_cast<unsigned*>(ylc + byt2) = packbf2(v.z, v.w);
        }
    }
    if (tid < QB * (K2 - H_DIM) / 2) {   // zero-fill k=230..255: 32 rows x 13 pairs
        int r = tid & 31, c = H_DIM + 2 * (tid >> 5);
        int byt = ((r << 9) + (c << 1)) ^ ((r & 7) << 4);
        *reinterpret_cast<unsigned*>(ylc + byt) = 0u;
    }

    // ---- label prefetch: issue AFTER staging reads, consume in epilogue ----
    int labs[2][4];
    {
        const size_t ob = (size_t)(s_base + lh * 4) * Q_DIM + q0 + lm;
        #pragma unroll
        for (int r = 0; r < 4; ++r) {
            labs[0][r] = label[ob + (size_t)r * Q_DIM];
            labs[1][r] = label[ob + (size_t)r * Q_DIM + 16];
        }
    }

    // ---- A-frags + a[s] in registers (pre-barrier; overlaps y staging) ----
    // Lane's A row = s_base+lm; k = ks*32 + lh*8 + e. float2 pairs (8B-aligned
    // always: rows start at even f32 offsets, k even; pair valid iff k<230).
    // w loads are uniform across the 16 lm-lanes -> L1 broadcast.
    short8 afr[8];
    {
        float ap = 0.f;
        const float* xrow = x + (size_t)(s_base + lm) * H_DIM;
        #pragma unroll
        for (int ks = 0; ks < 8; ++ks) {
            const int kof = ks * 32 + lh * 8;
            short8 a;
            #pragma unroll
            for (int j = 0; j < 4; ++j) {
                int k = kof + 2 * j;
                float2 x2 = {0.f, 0.f}, w2 = {0.f, 0.f};
                if (k < H_DIM) {
                    x2 = *reinterpret_cast<const float2*>(xrow + k);
                    w2 = *reinterpret_cast<const float2*>(w + k);
                }
                float p0 = w2.x * x2.x, p1 = w2.y * x2.y;
                a[2 * j]     = (short)bf16bits(p0);
                a[2 * j + 1] = (short)bf16bits(p1);
                ap = fmaf(p1, x2.y, fmaf(p0, x2.x, ap));   // w*x^2 (f32)
            }
            afr[ks] = a;
        }
        // combine the 4 lh-quarters (fixed order, deterministic)
        ap += __shfl_xor(ap, 16, 64);
        ap += __shfl_xor(ap, 32, 64);
        if (lh == 0) asl[s_base + lm] = ap;
    }

    __syncthreads();

    // ---- c[q] partials: r=tid&31 (q-row), ch=tid>>5 (16 k each) ----
    {
        const int r = tid & 31, ch = tid >> 5;     // ch in 0..15
        const int k0 = ch * 16;
        int byt0 = ((r << 9) + (k0 << 1)) ^ ((r & 7) << 4);
        int byt1 = ((r << 9) + ((k0 + 8) << 1)) ^ ((r & 7) << 4);
        short8 v8a = *reinterpret_cast<const short8*>(ylc + byt0);
        short8 v8b = *reinterpret_cast<const short8*>(ylc + byt1);
        float p = 0.f;
        #pragma unroll
        for (int j = 0; j < 8; ++j) {
            float va = bf16_to_f32(v8a[j]);
            float wa = (k0 + j < H_DIM) ? w[k0 + j] : 0.f;
            p = fmaf(wa * va, va, p);
        }
        #pragma unroll
        for (int j = 0; j < 8; ++j) {
            float vb = bf16_to_f32(v8b[j]);
            float wb = (k0 + 8 + j < H_DIM) ? w[k0 + 8 + j] : 0.f;
            p = fmaf(wb * vb, vb, p);
        }
        cpart[ch][r] = p;
    }
    __syncthreads();
    if (tid < QB) {
        float c = 0.f;
        #pragma unroll
        for (int ch = 0; ch < 16; ++ch) c += cpart[ch][tid];
        cq[tid] = c + bptr[0];                     // fold bias in
    }
    __syncthreads();

    // ---- MFMA k-loop: wave computes 16 s x 32 q (2 accs, A from registers) ----
    f32x4 acc0 = {0.f, 0.f, 0.f, 0.f};
    f32x4 acc1 = {0.f, 0.f, 0.f, 0.f};
    #pragma unroll
    for (int ks = 0; ks < K2 / 32; ++ks) {
        const int kof = ks * 32 + lh * 8;
        int byt0 = ((lm << 9) + (kof << 1)) ^ ((lm & 7) << 4);
        int byt1 = (((lm + 16) << 9) + (kof << 1)) ^ ((lm & 7) << 4);
        short8 bf0 = *reinterpret_cast<const short8*>(ylc + byt0);
        short8 bf1 = *reinterpret_cast<const short8*>(ylc + byt1);
        acc0 = __builtin_amdgcn_mfma_f32_16x16x32_bf16(afr[ks], bf0, acc0, 0, 0, 0);
        acc1 = __builtin_amdgcn_mfma_f32_16x16x32_bf16(afr[ks], bf1, acc1, 0, 0, 0);
    }

    // ---- epilogue: z = a[s]+c[q]+b-2*dot ; sigmoid -> out ; BCE partial ----
    // bce = z*(1-lab) + log(1+exp(-z)), sharing exp(-z) with the sigmoid.
    float lsum = 0.f;
    const float cq0 = cq[lm], cq1 = cq[lm + 16];
    #pragma unroll
    for (int r = 0; r < 4; ++r) {
        int s = s_base + lh * 4 + r;               // D row=(l>>4)*4+r, col=l&15
        size_t o = (size_t)s * Q_DIM + q0 + lm;
        {
            float z = asl[s] + cq0 - 2.0f * acc0[r];
            float ez = __expf(-z);
            out[o] = 1.0f / (1.0f + ez);
            float lab = (float)labs[0][r];
            lsum += z * (1.0f - lab) + __logf(1.0f + ez);
        }
        {
            float z = asl[s] + cq1 - 2.0f * acc1[r];
            float ez = __expf(-z);
            out[o + 16] = 1.0f / (1.0f + ez);
            float lab = (float)labs[1][r];
            lsum += z * (1.0f - lab) + __logf(1.0f + ez);
        }
    }
    #pragma unroll
    for (int off = 32; off >= 1; off >>= 1) lsum += __shfl_down(lsum, off, 64);
    if (l == 0) lred[wid] = lsum;
    __syncthreads();
    if (tid == 0) {
        float blk = 0.f;
        #pragma unroll
        for (int i = 0; i < 8; ++i) blk += lred[i];
        lossws[blockIdx.x] = blk;
    }
}

// ---------------- Kernel 2: deterministic loss reduce ----------------
__global__ __launch_bounds__(256) void loss_reduce_kernel(
    const float* __restrict__ lossws, float* __restrict__ out)
{
    __shared__ float lred[4];
    const int tid = threadIdx.x;
    float p = lossws[tid];                         // NBLK=256 partials
    #pragma unroll
    for (int off = 32; off >= 1; off >>= 1) p += __shfl_down(p, off, 64);
    if ((tid & 63) == 0) lred[tid >> 6] = p;
    __syncthreads();
    if (tid == 0)
        out[SQ] = (lred[0] + lred[1] + lred[2] + lred[3]) * (1.0f / (float)SQ);
}

extern "C" void kernel_launch(void* const* d_in, const int* in_sizes, int n_in,
                              void* d_out, int out_size, void* d_ws, size_t ws_size,
                              hipStream_t stream) {
    const float* x = (const float*)d_in[0];     // [128,230]
    const float* y = (const float*)d_in[1];     // [8192,230]
    const int* label = (const int*)d_in[2];     // [128,8192]
    const float* w = (const float*)d_in[3];     // [230]
    const float* b = (const float*)d_in[4];     // [1]
    float* out = (float*)d_out;                 // [128*8192 + 1]

    float* lossws = (float*)d_ws;               // [256]

    main_kernel<<<NBLK, 512, 0, stream>>>(x, y, label, w, b, out, lossws);
    loss_reduce_kernel<<<1, 256, 0, stream>>>(lossws, out);
}